// Round 10
// baseline (1515.647 us; speedup 1.0000x reference)
//
#include <hip/hip_runtime.h>
#include <hip/hip_bf16.h>

typedef __attribute__((ext_vector_type(4))) int int4v;

#define MFMA_I8(a, b, c) __builtin_amdgcn_mfma_i32_32x32x16_i8 /*unused*/
#undef MFMA_I8
#define MFMA_I8(a, b, c) __builtin_amdgcn_mfma_i32_16x16x64_i8((a), (b), (c), 0, 0, 0)
#define GLDS16(g, l)                                                                        \
  __builtin_amdgcn_global_load_lds((const __attribute__((address_space(1))) void*)(g),      \
                                   (__attribute__((address_space(3))) void*)(l), 16, 0, 0)
#define SBAR() __builtin_amdgcn_s_barrier()
#define SCHED0() __builtin_amdgcn_sched_barrier(0)

static constexpr int NTOK = 4096;
static constexpr int DDIM = 4096;
static constexpr int FDIM = 11008;

// ---------------------------------------------------------------- utilities

__device__ __forceinline__ float wave_max64(float m) {
#pragma unroll
  for (int o = 32; o > 0; o >>= 1) m = fmaxf(m, __shfl_xor(m, o));
  return m;
}

__global__ void zero_slots(unsigned* s) {
  if (threadIdx.x < 16) s[threadIdx.x] = 0u;
}

__device__ __forceinline__ void absmax_body(const float* __restrict__ p, int n4,
                                            unsigned* __restrict__ slot) {
  float m = 0.f;
  const int stride = gridDim.x * blockDim.x;
  for (int i = blockIdx.x * blockDim.x + threadIdx.x; i < n4; i += stride) {
    float4 v = reinterpret_cast<const float4*>(p)[i];
    m = fmaxf(fmaxf(fabsf(v.x), fabsf(v.y)), fmaxf(fmaxf(fabsf(v.z), fabsf(v.w)), m));
  }
  m = wave_max64(m);
  __shared__ float wm[4];
  const int lane = threadIdx.x & 63, w = threadIdx.x >> 6;
  if (lane == 0) wm[w] = m;
  __syncthreads();
  if (threadIdx.x == 0) {
    m = fmaxf(fmaxf(wm[0], wm[1]), fmaxf(wm[2], wm[3]));
    atomicMax(slot, __float_as_uint(m));
  }
}

__global__ void absmax4(const float* x, const float* w1, const float* w3, const float* w2,
                        unsigned* slots, int n4x, int n4w) {
  const int seg = blockIdx.y;
  const float* p = (seg == 0) ? x : (seg == 1) ? w1 : (seg == 2) ? w3 : w2;
  absmax_body(p, seg == 0 ? n4x : n4w, slots + seg);
}

__device__ __forceinline__ void quant_body(const float* __restrict__ in,
                                           unsigned* __restrict__ out, int n4,
                                           const unsigned* __restrict__ slot) {
  const float s = fmaxf(__uint_as_float(*slot), 1e-8f) / 127.0f;
  const int stride = gridDim.x * blockDim.x;
  for (int i = blockIdx.x * blockDim.x + threadIdx.x; i < n4; i += stride) {
    float4 v = reinterpret_cast<const float4*>(in)[i];
    const int q0 = (int)rintf(v.x / s), q1 = (int)rintf(v.y / s);
    const int q2 = (int)rintf(v.z / s), q3 = (int)rintf(v.w / s);
    out[i] = (unsigned)(q0 & 255) | ((unsigned)(q1 & 255) << 8) |
             ((unsigned)(q2 & 255) << 16) | ((unsigned)(q3 & 255) << 24);
  }
}

// FRAG-MAJOR weight quant for the GLU B-operands (F x D, D=4096).
// Output u32x4 slot u (16 B): block = u>>8 (= p*32 + kt), sidx = u&255,
// fi = sidx>>6 (= kk*2+n), l = sidx&63.
// Holds B[p*32 + n*16 + (l&15)][kt*128 + kk*64 + (l>>4)*16 .. +15] as i8.
__device__ __forceinline__ void quantW_frag_body(const float* __restrict__ in,
                                                 int4v* __restrict__ out,
                                                 const unsigned* __restrict__ slot) {
  const float s = fmaxf(__uint_as_float(*slot), 1e-8f) / 127.0f;
  const int total = FDIM * (DDIM / 16);  // 2,818,048
  const int stride = gridDim.x * blockDim.x;
  for (int u = blockIdx.x * blockDim.x + threadIdx.x; u < total; u += stride) {
    const int block = u >> 8;
    const int sidx = u & 255;
    const int fi = sidx >> 6;
    const int l = sidx & 63;
    const int p = block >> 5;   // NKT = DDIM/128 = 32
    const int kt = block & 31;
    const int f = p * 32 + (fi & 1) * 16 + (l & 15);
    const int k0 = kt * 128 + (fi >> 1) * 64 + (l >> 4) * 16;
    const float4* src = reinterpret_cast<const float4*>(in + (size_t)f * DDIM + k0);
    unsigned r[4];
#pragma unroll
    for (int j = 0; j < 4; ++j) {
      float4 v = src[j];
      const int q0 = (int)rintf(v.x / s), q1 = (int)rintf(v.y / s);
      const int q2 = (int)rintf(v.z / s), q3 = (int)rintf(v.w / s);
      r[j] = (unsigned)(q0 & 255) | ((unsigned)(q1 & 255) << 8) |
             ((unsigned)(q2 & 255) << 16) | ((unsigned)(q3 & 255) << 24);
    }
    out[u] = (int4v){(int)r[0], (int)r[1], (int)r[2], (int)r[3]};
  }
}

__global__ void quant4(const float* x, const float* w1, const float* w3, const float* w2,
                       unsigned* qx, unsigned* qw1, unsigned* qw3, unsigned* qw2,
                       const unsigned* slots, int n4x, int n4w) {
  const int seg = blockIdx.y;
  if (seg == 0) quant_body(x, qx, n4x, slots + 0);
  else if (seg == 1) quantW_frag_body(w1, (int4v*)qw1, slots + 1);
  else if (seg == 2) quantW_frag_body(w3, (int4v*)qw3, slots + 2);
  else quant_body(w2, qw2, n4w, slots + 3);
}

__global__ void quant_kernel(const float* __restrict__ in, unsigned* __restrict__ out,
                             int n4, const unsigned* __restrict__ slot) {
  quant_body(in, out, n4, slot);
}

// ----------------- fused gate+up GLU GEMM: B in REGISTERS (frag-major qw)
// H[M][F] = (A.B1^T*s1)*silu(A.B3^T*s3). Tile 128x256, 8 waves 1M x 8N:
// wave w owns cols w*32..+31; its B3/B1 frags load straight from the
// frag-major buffers with coalesced global_load_dwordx4 -> NO LDS for B.
// LDS = A only: 2 bufs x 16 KB (A[128][128B], XOR-swizzled granules).
// Per tile: vmcnt(8) [drain A(kt)+B(kt); B(kt+1)'s 8 reg-loads STAY in
// flight across the barrier]; SBAR; stage A(kt+1)->other buf; 16 a-frag
// ds_reads + 64 MFMA (B from regs); issue B(kt+2) into just-freed cur regs.
// B double-buffer in named reg arrays, 2-tile unrolled loop (rule #20).
__global__ __launch_bounds__(512, 2) void gemm_glu(
    const signed char* __restrict__ Aq, const signed char* __restrict__ B3f,
    const signed char* __restrict__ B1f, float* __restrict__ H,
    const unsigned* __restrict__ slots, unsigned* __restrict__ hslot) {
  constexpr int K = DDIM;
  constexpr int NT = K >> 7;  // 32 (even)
  __shared__ char lds[32768];

  const int t = threadIdx.x;
  const int l = t & 63;
  const int w = t >> 6;  // wave = N-panel owner

  // XCD-aware column-major chunking (nwg = 43*32 = 1376, %8==0)
  const int gx = gridDim.x, gy = gridDim.y;
  const int nwg = gx * gy;
  const int i0 = blockIdx.y * gx + blockIdx.x;
  const int cid = (i0 & 7) * (nwg >> 3) + (i0 >> 3);
  const int rowA0 = (cid % gy) << 7;  // 128-row tile
  const int colB0 = (cid / gy) << 8;  // 256-col tile

  // A staging (cooperative GLDS, swizzled source, linear dest)
  const int rlA = t >> 3;
  const int glA = (t & 7) ^ (rlA & 7);
  const signed char* aP = Aq + (size_t)(rowA0 + rlA) * K + glA * 16;
  const size_t r64 = (size_t)64 * K;
  const int stW = w * 1024;

  // B bases (frag-major blocks of 4 KB, block index = p*32 + kt)
  const int p0 = (colB0 >> 5) + w;
  const signed char* w3b = B3f + (size_t)p0 * 32 * 4096 + l * 16;
  const signed char* w1b = B1f + (size_t)p0 * 32 * 4096 + l * 16;

#define STAGE_A(KT, BUF)                                  \
  do {                                                    \
    const size_t kO_ = (size_t)(KT) * 128;                \
    GLDS16(aP + kO_, &lds[(BUF) + stW]);                  \
    GLDS16(aP + r64 + kO_, &lds[(BUF) + 8192 + stW]);     \
  } while (0)

#define LOADB(KT, B3A, B1A)                                      \
  do {                                                           \
    const signed char* p3_ = w3b + (size_t)(KT)*4096;            \
    const signed char* p1_ = w1b + (size_t)(KT)*4096;            \
    B3A[0][0] = *(const int4v*)(p3_);                            \
    B3A[0][1] = *(const int4v*)(p3_ + 1024);                     \
    B3A[1][0] = *(const int4v*)(p3_ + 2048);                     \
    B3A[1][1] = *(const int4v*)(p3_ + 3072);                     \
    B1A[0][0] = *(const int4v*)(p1_);                            \
    B1A[0][1] = *(const int4v*)(p1_ + 1024);                     \
    B1A[1][0] = *(const int4v*)(p1_ + 2048);                     \
    B1A[1][1] = *(const int4v*)(p1_ + 3072);                     \
  } while (0)

#define LDSF(BASE, R, G)                                                      \
  (*reinterpret_cast<const int4v*>(                                           \
      &lds[(BASE) + (R)*128 + (((G) ^ ((R)&7)) << 4)]))

  int4v acc3[8][2], acc1[8][2];
#pragma unroll
  for (int m = 0; m < 8; ++m)
#pragma unroll
    for (int n = 0; n < 2; ++n) {
      acc3[m][n] = (int4v){0, 0, 0, 0};
      acc1[m][n] = (int4v){0, 0, 0, 0};
    }

  const int lr = l & 15;
  const int cr = l >> 4;

  int4v bc3[2][2], bc1[2][2], bn3[2][2], bn1[2][2];

  // prologue: A(0) -> buf0 (2 GLDS); B(0) -> cur regs; B(1) -> nxt regs
  STAGE_A(0, 0);
  LOADB(0, bc3, bc1);
  LOADB(1, bn3, bn1);

#define TILE(KT, C3, C1)                                                       \
  do {                                                                         \
    const int rb_ = ((KT)&1) * 16384;                                          \
    SCHED0();                                                                  \
    if ((KT) + 1 < NT) {                                                       \
      asm volatile("s_waitcnt vmcnt(8)" ::: "memory");                         \
    } else {                                                                   \
      asm volatile("s_waitcnt vmcnt(0)" ::: "memory");                         \
    }                                                                          \
    SBAR();                                                                    \
    SCHED0();                                                                  \
    if ((KT) + 1 < NT) STAGE_A((KT) + 1, rb_ ^ 16384);                         \
    int4v a_[8];                                                               \
    _Pragma("unroll") for (int m = 0; m < 8; ++m)                              \
        a_[m] = LDSF(rb_, m * 16 + lr, cr);                                    \
    __builtin_amdgcn_s_setprio(1);                                             \
    _Pragma("unroll") for (int m = 0; m < 8; ++m) {                            \
      acc3[m][0] = MFMA_I8(a_[m], C3[0][0], acc3[m][0]);                       \
      acc3[m][1] = MFMA_I8(a_[m], C3[0][1], acc3[m][1]);                       \
      acc1[m][0] = MFMA_I8(a_[m], C1[0][0], acc1[m][0]);                       \
      acc1[m][1] = MFMA_I8(a_[m], C1[0][1], acc1[m][1]);                       \
    }                                                                          \
    __builtin_amdgcn_s_setprio(0);                                             \
    _Pragma("unroll") for (int m = 0; m < 8; ++m)                              \
        a_[m] = LDSF(rb_, m * 16 + lr, 4 + cr);                                \
    __builtin_amdgcn_s_setprio(1);                                             \
    _Pragma("unroll") for (int m = 0; m < 8; ++m) {                            \
      acc3[m][0] = MFMA_I8(a_[m], C3[1][0], acc3[m][0]);                       \
      acc3[m][1] = MFMA_I8(a_[m], C3[1][1], acc3[m][1]);                       \
      acc1[m][0] = MFMA_I8(a_[m], C1[1][0], acc1[m][0]);                       \
      acc1[m][1] = MFMA_I8(a_[m], C1[1][1], acc1[m][1]);                       \
    }                                                                          \
    __builtin_amdgcn_s_setprio(0);                                             \
    if ((KT) + 2 < NT) LOADB((KT) + 2, C3, C1);                                \
  } while (0)

  for (int kt = 0; kt < NT; kt += 2) {
    TILE(kt, bc3, bc1);
    TILE(kt + 1, bn3, bn1);
  }

  // ------------------------------------------------------------- epilogue
  const float sx = fmaxf(__uint_as_float(slots[0]), 1e-8f) / 127.0f;
  const float sw1 = fmaxf(__uint_as_float(slots[1]), 1e-8f) / 127.0f;
  const float sw3 = fmaxf(__uint_as_float(slots[2]), 1e-8f) / 127.0f;
  const float s3 = sx * sw3, s1 = sx * sw1;
  const int crow0 = rowA0 + ((l >> 4) << 2);
  const int ccol0 = colB0 + w * 32 + lr;
  float hmax = 0.f;
#pragma unroll
  for (int m = 0; m < 8; ++m)
#pragma unroll
    for (int n = 0; n < 2; ++n)
#pragma unroll
      for (int j = 0; j < 4; ++j) {
        const int row = crow0 + m * 16 + j;
        const int col = ccol0 + n * 16;
        const float g = (float)acc3[m][n][j] * s3;
        const float gate = g / (1.f + expf(-g));  // silu
        const float h = (float)acc1[m][n][j] * s1 * gate;
        H[(size_t)row * FDIM + col] = h;
        hmax = fmaxf(hmax, fabsf(h));
      }
  hmax = wave_max64(hmax);
  if (l == 0) atomicMax(hslot, __float_as_uint(hmax));
#undef STAGE_A
#undef LOADB
#undef LDSF
#undef TILE
}

// ------------------------------- 256x256 down GEMM, BK=128, 1 barrier/tile
// out[M][N] = s * A[M][K].B[N][K]^T (round-9 measured structure, unchanged).
__global__ __launch_bounds__(512, 2) void gemm_down(
    const signed char* __restrict__ Aq, const signed char* __restrict__ Bq,
    float* __restrict__ C, const unsigned* __restrict__ slots, int sA, int sB,
    int K, int ldc) {
  __shared__ char lds[131072];  // 2 x 65536

  const int t = threadIdx.x;
  const int l = t & 63;
  const int w = t >> 6;
  const int wm = w >> 2;  // 0..1
  const int wn = w & 3;   // 0..3

  const int gx = gridDim.x, gy = gridDim.y;
  const int nwg = gx * gy;
  const int i0 = blockIdx.y * gx + blockIdx.x;
  const int cid = (i0 & 7) * (nwg >> 3) + (i0 >> 3);
  const int rowA0 = (cid % gy) << 8;
  const int colB0 = (cid / gy) << 8;

  const int rl = t >> 3;
  const int gl = (t & 7) ^ (rl & 7);
  const signed char* aP = Aq + (size_t)(rowA0 + rl) * K + gl * 16;
  const signed char* bP = Bq + (size_t)(colB0 + rl) * K + gl * 16;
  const size_t r64 = (size_t)64 * K;
  const int stW = w * 1024;

#define STAGE8(KO, BASE)                                             \
  do {                                                               \
    GLDS16(aP + (KO), &lds[(BASE) + stW]);                           \
    GLDS16(aP + r64 + (KO), &lds[(BASE) + 8192 + stW]);              \
    GLDS16(aP + 2 * r64 + (KO), &lds[(BASE) + 16384 + stW]);         \
    GLDS16(aP + 3 * r64 + (KO), &lds[(BASE) + 24576 + stW]);         \
    GLDS16(bP + (KO), &lds[(BASE) + 32768 + stW]);                   \
    GLDS16(bP + r64 + (KO), &lds[(BASE) + 40960 + stW]);             \
    GLDS16(bP + 2 * r64 + (KO), &lds[(BASE) + 49152 + stW]);         \
    GLDS16(bP + 3 * r64 + (KO), &lds[(BASE) + 57344 + stW]);         \
  } while (0)

#define LDSF(BASE, ROW, G)                                                    \
  (*reinterpret_cast<const int4v*>(                                           \
      &lds[(BASE) + (ROW)*128 + (((G) ^ ((ROW)&7)) << 4)]))

  int4v acc[8][4];
#pragma unroll
  for (int m = 0; m < 8; ++m)
#pragma unroll
    for (int n = 0; n < 4; ++n) acc[m][n] = (int4v){0, 0, 0, 0};

  const int NT = K >> 7;  // 86
  const int arow = wm * 128 + (l & 15);
  const int brow = wn * 64 + (l & 15);
  const int cr = l >> 4;

  STAGE8(0, 0);

  for (int kt = 0; kt < NT; ++kt) {
    const int rb = (kt & 1) * 65536;
    SCHED0();
    asm volatile("s_waitcnt vmcnt(0)" ::: "memory");
    SBAR();
    SCHED0();

    if (kt + 1 < NT) STAGE8((size_t)(kt + 1) * 128, rb ^ 65536);

#pragma unroll
    for (int kk = 0; kk < 2; ++kk) {
      int4v a[8], b[4];
#pragma unroll
      for (int m = 0; m < 8; ++m) a[m] = LDSF(rb, arow + m * 16, kk * 4 + cr);
#pragma unroll
      for (int n = 0; n < 4; ++n) b[n] = LDSF(rb + 32768, brow + n * 16, kk * 4 + cr);
      __builtin_amdgcn_s_setprio(1);
#pragma unroll
      for (int m = 0; m < 8; ++m)
#pragma unroll
        for (int n = 0; n < 4; ++n) acc[m][n] = MFMA_I8(a[m], b[n], acc[m][n]);
      __builtin_amdgcn_s_setprio(0);
    }
  }

  const float sa = fmaxf(__uint_as_float(slots[sA]), 1e-8f) / 127.0f;
  const float sb2 = fmaxf(__uint_as_float(slots[sB]), 1e-8f) / 127.0f;
  const float s = sa * sb2;
  const int crow0 = rowA0 + wm * 128 + ((l >> 4) << 2);
  const int ccol0 = colB0 + wn * 64 + (l & 15);
#pragma unroll
  for (int m = 0; m < 8; ++m)
#pragma unroll
    for (int n = 0; n < 4; ++n)
#pragma unroll
      for (int j = 0; j < 4; ++j) {
        const int row = crow0 + m * 16 + j;
        const int col = ccol0 + n * 16;
        C[(size_t)row * ldc + col] = (float)acc[m][n][j] * s;
      }
#undef STAGE8
#undef LDSF
}

// ------------------------------------------------------------------- launch

extern "C" void kernel_launch(void* const* d_in, const int* in_sizes, int n_in,
                              void* d_out, int out_size, void* d_ws, size_t ws_size,
                              hipStream_t stream) {
  const float* x = (const float*)d_in[0];
  const float* w1 = (const float*)d_in[1];
  const float* w3 = (const float*)d_in[2];
  const float* w2 = (const float*)d_in[3];
  float* out = (float*)d_out;
  char* ws = (char*)d_ws;

  unsigned* slots = (unsigned*)ws;  // [0]=x [1]=w1 [2]=w3 [3]=w2 [4]=h absmax
  size_t off = 256;
  signed char* qx = (signed char*)(ws + off);
  off += (size_t)NTOK * DDIM;
  signed char* qw3 = (signed char*)(ws + off);  // frag-major
  off += (size_t)FDIM * DDIM;
  signed char* qw1 = (signed char*)(ws + off);  // frag-major
  off += (size_t)FDIM * DDIM;
  signed char* qw2 = (signed char*)(ws + off);  // linear
  off += (size_t)FDIM * DDIM;
  float* H = (float*)(ws + off);
  off += (size_t)NTOK * FDIM * 4;
  signed char* qh = (signed char*)(ws + off);
  off += (size_t)NTOK * FDIM;  // ~385 MB total

  const int n4x = NTOK * DDIM / 4;
  const int n4w = FDIM * DDIM / 4;
  const int n4h = NTOK * FDIM / 4;

  zero_slots<<<1, 64, 0, stream>>>(slots);
  absmax4<<<dim3(512, 4), 256, 0, stream>>>(x, w1, w3, w2, slots, n4x, n4w);
  quant4<<<dim3(2048, 4), 256, 0, stream>>>(x, w1, w3, w2, (unsigned*)qx, (unsigned*)qw1,
                                            (unsigned*)qw3, (unsigned*)qw2, slots, n4x, n4w);

  // fused gate+up: H = (x.w1^T*s1) * silu(x.w3^T*s3), + absmax(H)
  const dim3 gGlu(FDIM / 256, NTOK / 128);  // 43 x 32 = 1376 wgs
  gemm_glu<<<gGlu, 512, 0, stream>>>(qx, qw3, qw1, H, slots, slots + 4);
  quant_kernel<<<2048, 256, 0, stream>>>(H, (unsigned*)qh, n4h, slots + 4);
  // down: out = (h.w2^T) * s
  const dim3 gDn(DDIM / 256, NTOK / 256);  // 16 x 16 = 256 wgs
  gemm_down<<<gDn, 512, 0, stream>>>(qh, qw2, out, slots, 4, 3, FDIM, DDIM);
}

// Round 11
// 887.204 us; speedup vs baseline: 1.7083x; 1.7083x over previous
//
#include <hip/hip_runtime.h>
#include <hip/hip_bf16.h>

typedef __attribute__((ext_vector_type(4))) int int4v;

#define MFMA_I8(a, b, c) __builtin_amdgcn_mfma_i32_16x16x64_i8((a), (b), (c), 0, 0, 0)
#define GLDS16(g, l)                                                                        \
  __builtin_amdgcn_global_load_lds((const __attribute__((address_space(1))) void*)(g),      \
                                   (__attribute__((address_space(3))) void*)(l), 16, 0, 0)
#define SBAR() __builtin_amdgcn_s_barrier()
#define SCHED0() __builtin_amdgcn_sched_barrier(0)

static constexpr int NTOK = 4096;
static constexpr int DDIM = 4096;
static constexpr int FDIM = 11008;

// ---------------------------------------------------------------- utilities

__device__ __forceinline__ float wave_max64(float m) {
#pragma unroll
  for (int o = 32; o > 0; o >>= 1) m = fmaxf(m, __shfl_xor(m, o));
  return m;
}

__global__ void zero_slots(unsigned* s) {
  if (threadIdx.x < 16) s[threadIdx.x] = 0u;
}

__device__ __forceinline__ void absmax_body(const float* __restrict__ p, int n4,
                                            unsigned* __restrict__ slot) {
  float m = 0.f;
  const int stride = gridDim.x * blockDim.x;
  for (int i = blockIdx.x * blockDim.x + threadIdx.x; i < n4; i += stride) {
    float4 v = reinterpret_cast<const float4*>(p)[i];
    m = fmaxf(fmaxf(fabsf(v.x), fabsf(v.y)), fmaxf(fmaxf(fabsf(v.z), fabsf(v.w)), m));
  }
  m = wave_max64(m);
  __shared__ float wm[4];
  const int lane = threadIdx.x & 63, w = threadIdx.x >> 6;
  if (lane == 0) wm[w] = m;
  __syncthreads();
  if (threadIdx.x == 0) {
    m = fmaxf(fmaxf(wm[0], wm[1]), fmaxf(wm[2], wm[3]));
    atomicMax(slot, __float_as_uint(m));
  }
}

__global__ void absmax4(const float* x, const float* w1, const float* w3, const float* w2,
                        unsigned* slots, int n4x, int n4w) {
  const int seg = blockIdx.y;
  const float* p = (seg == 0) ? x : (seg == 1) ? w1 : (seg == 2) ? w3 : w2;
  absmax_body(p, seg == 0 ? n4x : n4w, slots + seg);
}

__device__ __forceinline__ void quant_body(const float* __restrict__ in,
                                           unsigned* __restrict__ out, int n4,
                                           const unsigned* __restrict__ slot) {
  const float s = fmaxf(__uint_as_float(*slot), 1e-8f) / 127.0f;
  const int stride = gridDim.x * blockDim.x;
  for (int i = blockIdx.x * blockDim.x + threadIdx.x; i < n4; i += stride) {
    float4 v = reinterpret_cast<const float4*>(in)[i];
    const int q0 = (int)rintf(v.x / s), q1 = (int)rintf(v.y / s);
    const int q2 = (int)rintf(v.z / s), q3 = (int)rintf(v.w / s);
    out[i] = (unsigned)(q0 & 255) | ((unsigned)(q1 & 255) << 8) |
             ((unsigned)(q2 & 255) << 16) | ((unsigned)(q3 & 255) << 24);
  }
}

// FRAG-MAJOR weight quant for the GLU B-operands (layout verified in R10).
// u32x4 slot u: block = u>>8 (= p*32 + kt), fi = (u&255)>>6, l = u&63.
// Holds B[p*32 + (fi&1)*16 + (l&15)][kt*128 + (fi>>1)*64 + (l>>4)*16 ..+15].
__device__ __forceinline__ void quantW_frag_body(const float* __restrict__ in,
                                                 int4v* __restrict__ out,
                                                 const unsigned* __restrict__ slot) {
  const float s = fmaxf(__uint_as_float(*slot), 1e-8f) / 127.0f;
  const int total = FDIM * (DDIM / 16);
  const int stride = gridDim.x * blockDim.x;
  for (int u = blockIdx.x * blockDim.x + threadIdx.x; u < total; u += stride) {
    const int block = u >> 8;
    const int sidx = u & 255;
    const int fi = sidx >> 6;
    const int l = sidx & 63;
    const int p = block >> 5;
    const int kt = block & 31;
    const int f = p * 32 + (fi & 1) * 16 + (l & 15);
    const int k0 = kt * 128 + (fi >> 1) * 64 + (l >> 4) * 16;
    const float4* src = reinterpret_cast<const float4*>(in + (size_t)f * DDIM + k0);
    unsigned r[4];
#pragma unroll
    for (int j = 0; j < 4; ++j) {
      float4 v = src[j];
      const int q0 = (int)rintf(v.x / s), q1 = (int)rintf(v.y / s);
      const int q2 = (int)rintf(v.z / s), q3 = (int)rintf(v.w / s);
      r[j] = (unsigned)(q0 & 255) | ((unsigned)(q1 & 255) << 8) |
             ((unsigned)(q2 & 255) << 16) | ((unsigned)(q3 & 255) << 24);
    }
    out[u] = (int4v){(int)r[0], (int)r[1], (int)r[2], (int)r[3]};
  }
}

__global__ void quant4(const float* x, const float* w1, const float* w3, const float* w2,
                       unsigned* qx, unsigned* qw1, unsigned* qw3, unsigned* qw2,
                       const unsigned* slots, int n4x, int n4w) {
  const int seg = blockIdx.y;
  if (seg == 0) quant_body(x, qx, n4x, slots + 0);
  else if (seg == 1) quantW_frag_body(w1, (int4v*)qw1, slots + 1);
  else if (seg == 2) quantW_frag_body(w3, (int4v*)qw3, slots + 2);
  else quant_body(w2, qw2, n4w, slots + 3);
}

__global__ void quant_kernel(const float* __restrict__ in, unsigned* __restrict__ out,
                             int n4, const unsigned* __restrict__ slot) {
  quant_body(in, out, n4, slot);
}

// ------------- fused gate+up GLU GEMM: B in regs, SINGLE-SET rotation (R10
// concept, register-pressure fixed: acc 128 + B 32 + a 32 ~= 210 VGPR).
// Tile 128x256, 8 waves 1M x 8N; wave w owns cols w*32..+31; B frags load
// coalesced from frag-major qw (no LDS for B). LDS = A only, 2 x 16 KB.
// Per tile kt: {vmcnt(8) [drain A(kt); B(kt+1) never force-drained]; SBAR};
// STAGE_A(kt+1); a-frags kk0; MFMA cluster1 (B[0] last use) ; reload next
// B[0]; a-frags kk1; MFMA cluster2 (B[1] last use); reload next B[1].
// B(kt) was loaded during tile kt-1 -> ~3/4-tile cover, mostly L2-hit.
__global__ __launch_bounds__(512, 2) void gemm_glu(
    const signed char* __restrict__ Aq, const signed char* __restrict__ B3f,
    const signed char* __restrict__ B1f, float* __restrict__ H,
    const unsigned* __restrict__ slots, unsigned* __restrict__ hslot) {
  constexpr int K = DDIM;
  constexpr int NT = K >> 7;  // 32
  __shared__ char lds[32768];

  const int t = threadIdx.x;
  const int l = t & 63;
  const int w = t >> 6;

  // XCD-aware column-major chunking (nwg = 1376, %8==0)
  const int gx = gridDim.x, gy = gridDim.y;
  const int nwg = gx * gy;
  const int i0 = blockIdx.y * gx + blockIdx.x;
  const int cid = (i0 & 7) * (nwg >> 3) + (i0 >> 3);
  const int rowA0 = (cid % gy) << 7;
  const int colB0 = (cid / gy) << 8;

  // A staging (cooperative GLDS, pre-swizzled source, linear dest)
  const int rlA = t >> 3;
  const int glA = (t & 7) ^ (rlA & 7);
  const signed char* aP = Aq + (size_t)(rowA0 + rlA) * K + glA * 16;
  const size_t r64 = (size_t)64 * K;
  const int stW = w * 1024;

  // B bases (frag-major 4 KB blocks, block = p*32 + kt)
  const int p0 = (colB0 >> 5) + w;
  const signed char* w3b = B3f + (size_t)p0 * 32 * 4096 + l * 16;
  const signed char* w1b = B1f + (size_t)p0 * 32 * 4096 + l * 16;

#define STAGE_A(KT, BUF)                               \
  do {                                                 \
    const size_t kO_ = (size_t)(KT) * 128;             \
    GLDS16(aP + kO_, &lds[(BUF) + stW]);               \
    GLDS16(aP + r64 + kO_, &lds[(BUF) + 8192 + stW]);  \
  } while (0)

#define LDSF(BASE, R, G)                                                      \
  (*reinterpret_cast<const int4v*>(                                           \
      &lds[(BASE) + (R)*128 + (((G) ^ ((R)&7)) << 4)]))

  int4v acc3[8][2], acc1[8][2];
#pragma unroll
  for (int m = 0; m < 8; ++m)
#pragma unroll
    for (int n = 0; n < 2; ++n) {
      acc3[m][n] = (int4v){0, 0, 0, 0};
      acc1[m][n] = (int4v){0, 0, 0, 0};
    }

  const int lr = l & 15;
  const int cr = l >> 4;

  // single-set B fragment registers (rotated in place each tile)
  int4v b3k0[2], b3k1[2], b1k0[2], b1k1[2];

  // prologue: A(0) -> buf0; B(0) -> regs
  STAGE_A(0, 0);
  {
    const signed char* p3_ = w3b;
    const signed char* p1_ = w1b;
    b3k0[0] = *(const int4v*)(p3_);
    b3k0[1] = *(const int4v*)(p3_ + 1024);
    b3k1[0] = *(const int4v*)(p3_ + 2048);
    b3k1[1] = *(const int4v*)(p3_ + 3072);
    b1k0[0] = *(const int4v*)(p1_);
    b1k0[1] = *(const int4v*)(p1_ + 1024);
    b1k1[0] = *(const int4v*)(p1_ + 2048);
    b1k1[1] = *(const int4v*)(p1_ + 3072);
  }

  for (int kt = 0; kt < NT; ++kt) {
    const int rb = (kt & 1) * 16384;
    const bool nx = (kt + 1 < NT);
    const signed char* p3n = w3b + (size_t)(kt + 1) * 4096;
    const signed char* p1n = w1b + (size_t)(kt + 1) * 4096;

    // ---- boundary: drain A(kt) only (queue: A(kt)x2 oldest, B in compiler's
    // per-reg tracking). Never force-drain B.
    SCHED0();
    asm volatile("s_waitcnt vmcnt(8)" ::: "memory");
    SBAR();
    SCHED0();

    if (nx) STAGE_A(kt + 1, rb ^ 16384);

    // kk=0: a-frags + MFMA cluster 1 (uses b*k0; last use)
    int4v a_[8];
#pragma unroll
    for (int m = 0; m < 8; ++m) a_[m] = LDSF(rb, m * 16 + lr, cr);
    __builtin_amdgcn_s_setprio(1);
#pragma unroll
    for (int m = 0; m < 8; ++m) {
      acc3[m][0] = MFMA_I8(a_[m], b3k0[0], acc3[m][0]);
      acc3[m][1] = MFMA_I8(a_[m], b3k0[1], acc3[m][1]);
      acc1[m][0] = MFMA_I8(a_[m], b1k0[0], acc1[m][0]);
      acc1[m][1] = MFMA_I8(a_[m], b1k0[1], acc1[m][1]);
    }
    __builtin_amdgcn_s_setprio(0);

    // reload next-tile k0 frags into the just-freed regs
    if (nx) {
      b3k0[0] = *(const int4v*)(p3n);
      b3k0[1] = *(const int4v*)(p3n + 1024);
      b1k0[0] = *(const int4v*)(p1n);
      b1k0[1] = *(const int4v*)(p1n + 1024);
    }

    // kk=1: a-frags + MFMA cluster 2 (uses b*k1; last use)
#pragma unroll
    for (int m = 0; m < 8; ++m) a_[m] = LDSF(rb, m * 16 + lr, 4 + cr);
    __builtin_amdgcn_s_setprio(1);
#pragma unroll
    for (int m = 0; m < 8; ++m) {
      acc3[m][0] = MFMA_I8(a_[m], b3k1[0], acc3[m][0]);
      acc3[m][1] = MFMA_I8(a_[m], b3k1[1], acc3[m][1]);
      acc1[m][0] = MFMA_I8(a_[m], b1k1[0], acc1[m][0]);
      acc1[m][1] = MFMA_I8(a_[m], b1k1[1], acc1[m][1]);
    }
    __builtin_amdgcn_s_setprio(0);

    if (nx) {
      b3k1[0] = *(const int4v*)(p3n + 2048);
      b3k1[1] = *(const int4v*)(p3n + 3072);
      b1k1[0] = *(const int4v*)(p1n + 2048);
      b1k1[1] = *(const int4v*)(p1n + 3072);
    }
  }

  // ------------------------------------------------------------- epilogue
  const float sx = fmaxf(__uint_as_float(slots[0]), 1e-8f) / 127.0f;
  const float sw1 = fmaxf(__uint_as_float(slots[1]), 1e-8f) / 127.0f;
  const float sw3 = fmaxf(__uint_as_float(slots[2]), 1e-8f) / 127.0f;
  const float s3 = sx * sw3, s1 = sx * sw1;
  const int crow0 = rowA0 + ((l >> 4) << 2);
  const int ccol0 = colB0 + w * 32 + lr;
  float hmax = 0.f;
#pragma unroll
  for (int m = 0; m < 8; ++m)
#pragma unroll
    for (int n = 0; n < 2; ++n)
#pragma unroll
      for (int j = 0; j < 4; ++j) {
        const int row = crow0 + m * 16 + j;
        const int col = ccol0 + n * 16;
        const float g = (float)acc3[m][n][j] * s3;
        const float gate = g / (1.f + expf(-g));  // silu
        const float h = (float)acc1[m][n][j] * s1 * gate;
        H[(size_t)row * FDIM + col] = h;
        hmax = fmaxf(hmax, fabsf(h));
      }
  hmax = wave_max64(hmax);
  if (l == 0) atomicMax(hslot, __float_as_uint(hmax));
#undef STAGE_A
#undef LDSF
}

// ------------------------------- 256x256 down GEMM, BK=128, 1 barrier/tile
// out[M][N] = s * A[M][K].B[N][K]^T (round-9 measured structure, unchanged).
__global__ __launch_bounds__(512, 2) void gemm_down(
    const signed char* __restrict__ Aq, const signed char* __restrict__ Bq,
    float* __restrict__ C, const unsigned* __restrict__ slots, int sA, int sB,
    int K, int ldc) {
  __shared__ char lds[131072];  // 2 x 65536

  const int t = threadIdx.x;
  const int l = t & 63;
  const int w = t >> 6;
  const int wm = w >> 2;  // 0..1
  const int wn = w & 3;   // 0..3

  const int gx = gridDim.x, gy = gridDim.y;
  const int nwg = gx * gy;
  const int i0 = blockIdx.y * gx + blockIdx.x;
  const int cid = (i0 & 7) * (nwg >> 3) + (i0 >> 3);
  const int rowA0 = (cid % gy) << 8;
  const int colB0 = (cid / gy) << 8;

  const int rl = t >> 3;
  const int gl = (t & 7) ^ (rl & 7);
  const signed char* aP = Aq + (size_t)(rowA0 + rl) * K + gl * 16;
  const signed char* bP = Bq + (size_t)(colB0 + rl) * K + gl * 16;
  const size_t r64 = (size_t)64 * K;
  const int stW = w * 1024;

#define STAGE8(KO, BASE)                                             \
  do {                                                               \
    GLDS16(aP + (KO), &lds[(BASE) + stW]);                           \
    GLDS16(aP + r64 + (KO), &lds[(BASE) + 8192 + stW]);              \
    GLDS16(aP + 2 * r64 + (KO), &lds[(BASE) + 16384 + stW]);         \
    GLDS16(aP + 3 * r64 + (KO), &lds[(BASE) + 24576 + stW]);         \
    GLDS16(bP + (KO), &lds[(BASE) + 32768 + stW]);                   \
    GLDS16(bP + r64 + (KO), &lds[(BASE) + 40960 + stW]);             \
    GLDS16(bP + 2 * r64 + (KO), &lds[(BASE) + 49152 + stW]);         \
    GLDS16(bP + 3 * r64 + (KO), &lds[(BASE) + 57344 + stW]);         \
  } while (0)

#define LDSF(BASE, ROW, G)                                                    \
  (*reinterpret_cast<const int4v*>(                                           \
      &lds[(BASE) + (ROW)*128 + (((G) ^ ((ROW)&7)) << 4)]))

  int4v acc[8][4];
#pragma unroll
  for (int m = 0; m < 8; ++m)
#pragma unroll
    for (int n = 0; n < 4; ++n) acc[m][n] = (int4v){0, 0, 0, 0};

  const int NT = K >> 7;  // 86
  const int arow = wm * 128 + (l & 15);
  const int brow = wn * 64 + (l & 15);
  const int cr = l >> 4;

  STAGE8(0, 0);

  for (int kt = 0; kt < NT; ++kt) {
    const int rb = (kt & 1) * 65536;
    SCHED0();
    asm volatile("s_waitcnt vmcnt(0)" ::: "memory");
    SBAR();
    SCHED0();

    if (kt + 1 < NT) STAGE8((size_t)(kt + 1) * 128, rb ^ 65536);

#pragma unroll
    for (int kk = 0; kk < 2; ++kk) {
      int4v a[8], b[4];
#pragma unroll
      for (int m = 0; m < 8; ++m) a[m] = LDSF(rb, arow + m * 16, kk * 4 + cr);
#pragma unroll
      for (int n = 0; n < 4; ++n) b[n] = LDSF(rb + 32768, brow + n * 16, kk * 4 + cr);
      __builtin_amdgcn_s_setprio(1);
#pragma unroll
      for (int m = 0; m < 8; ++m)
#pragma unroll
        for (int n = 0; n < 4; ++n) acc[m][n] = MFMA_I8(a[m], b[n], acc[m][n]);
      __builtin_amdgcn_s_setprio(0);
    }
  }

  const float sa = fmaxf(__uint_as_float(slots[sA]), 1e-8f) / 127.0f;
  const float sb2 = fmaxf(__uint_as_float(slots[sB]), 1e-8f) / 127.0f;
  const float s = sa * sb2;
  const int crow0 = rowA0 + wm * 128 + ((l >> 4) << 2);
  const int ccol0 = colB0 + wn * 64 + (l & 15);
#pragma unroll
  for (int m = 0; m < 8; ++m)
#pragma unroll
    for (int n = 0; n < 4; ++n)
#pragma unroll
      for (int j = 0; j < 4; ++j) {
        const int row = crow0 + m * 16 + j;
        const int col = ccol0 + n * 16;
        C[(size_t)row * ldc + col] = (float)acc[m][n][j] * s;
      }
#undef STAGE8
#undef LDSF
}

// ------------------------------------------------------------------- launch

extern "C" void kernel_launch(void* const* d_in, const int* in_sizes, int n_in,
                              void* d_out, int out_size, void* d_ws, size_t ws_size,
                              hipStream_t stream) {
  const float* x = (const float*)d_in[0];
  const float* w1 = (const float*)d_in[1];
  const float* w3 = (const float*)d_in[2];
  const float* w2 = (const float*)d_in[3];
  float* out = (float*)d_out;
  char* ws = (char*)d_ws;

  unsigned* slots = (unsigned*)ws;  // [0]=x [1]=w1 [2]=w3 [3]=w2 [4]=h absmax
  size_t off = 256;
  signed char* qx = (signed char*)(ws + off);
  off += (size_t)NTOK * DDIM;
  signed char* qw3 = (signed char*)(ws + off);  // frag-major
  off += (size_t)FDIM * DDIM;
  signed char* qw1 = (signed char*)(ws + off);  // frag-major
  off += (size_t)FDIM * DDIM;
  signed char* qw2 = (signed char*)(ws + off);  // linear
  off += (size_t)FDIM * DDIM;
  float* H = (float*)(ws + off);
  off += (size_t)NTOK * FDIM * 4;
  signed char* qh = (signed char*)(ws + off);
  off += (size_t)NTOK * FDIM;  // ~385 MB total

  const int n4x = NTOK * DDIM / 4;
  const int n4w = FDIM * DDIM / 4;
  const int n4h = NTOK * FDIM / 4;

  zero_slots<<<1, 64, 0, stream>>>(slots);
  absmax4<<<dim3(512, 4), 256, 0, stream>>>(x, w1, w3, w2, slots, n4x, n4w);
  quant4<<<dim3(2048, 4), 256, 0, stream>>>(x, w1, w3, w2, (unsigned*)qx, (unsigned*)qw1,
                                            (unsigned*)qw3, (unsigned*)qw2, slots, n4x, n4w);

  // fused gate+up: H = (x.w1^T*s1) * silu(x.w3^T*s3), + absmax(H)
  const dim3 gGlu(FDIM / 256, NTOK / 128);  // 43 x 32 = 1376 wgs
  gemm_glu<<<gGlu, 512, 0, stream>>>(qx, qw3, qw1, H, slots, slots + 4);
  quant_kernel<<<2048, 256, 0, stream>>>(H, (unsigned*)qh, n4h, slots + 4);
  // down: out = (h.w2^T) * s
  const dim3 gDn(DDIM / 256, NTOK / 256);  // 16 x 16 = 256 wgs
  gemm_down<<<gDn, 512, 0, stream>>>(qh, qw2, out, slots, 4, 3, FDIM, DDIM);
}